// Round 1
// baseline (346.240 us; speedup 1.0000x reference)
//
#include <hip/hip_runtime.h>
#include <math.h>

#define DIM   4096
#define NH    32
#define NKV   8
#define HD    128
#define KVBLK 256
#define TOPK  16
#define SCALE 0.08838834764831845f   // 1/sqrt(128)

// workspace layout (float offsets)
#define WS_Q   0        // 4096
#define WS_K   4096     // 1024
#define WS_V   5120     // 1024
#define WS_M   6144     // 32*32
#define WS_L   7168     // 32*32
#define WS_O   8192     // 32*32*128
#define WS_AO  139264   // 4096
// total 143360 floats = 573 KB

// ---------------------------------------------------------------------------
// K1: fused QKV GEMV + RoPE. 6144 rows (q:0..4095, k:4096..5119, v:5120..6143).
// One wave per row; block of 4 waves covers 4 consecutive rows so RoPE pairs
// (even,odd) are resident in the same block.
// ---------------------------------------------------------------------------
__global__ __launch_bounds__(256) void qkv_rope_kernel(
    const float* __restrict__ x,
    const float* __restrict__ wq,
    const float* __restrict__ wk,
    const float* __restrict__ wv,
    const float* __restrict__ cvec,
    const float* __restrict__ svec,
    float* __restrict__ ws)
{
  const int tid  = threadIdx.x;
  const int wave = tid >> 6;
  const int lane = tid & 63;
  const int base = blockIdx.x * 4;
  const int row  = base + wave;

  const float* W;
  int r;
  if (row < 4096)      { W = wq; r = row; }
  else if (row < 5120) { W = wk; r = row - 4096; }
  else                 { W = wv; r = row - 5120; }

  const float4* w4 = (const float4*)(W + (size_t)r * DIM);
  const float4* x4 = (const float4*)x;

  float acc = 0.f;
#pragma unroll
  for (int i = 0; i < 16; ++i) {
    float4 a = x4[lane + i * 64];
    float4 b = w4[lane + i * 64];
    acc += a.x * b.x + a.y * b.y + a.z * b.z + a.w * b.w;
  }
#pragma unroll
  for (int off = 32; off > 0; off >>= 1)
    acc += __shfl_xor(acc, off, 64);

  __shared__ float sval[4];
  if (lane == 0) sval[wave] = acc;
  __syncthreads();

  if (tid < 2) {
    const int pr    = tid;            // pair 0 or 1 within block
    const int row_e = base + 2 * pr;  // even row of the pair
    const float xe = sval[2 * pr];
    const float xo = sval[2 * pr + 1];
    if (row_e < 5120) {               // q or k row: apply RoPE
      const int j   = (row_e & (HD - 1)) >> 1;  // pair index within head
      const float c = cvec[j], s = svec[j];
      const float oe = xe * c - xo * s;
      const float oo = xe * s + xo * c;
      if (row_e < 4096) {
        ws[WS_Q + row_e]     = oe;
        ws[WS_Q + row_e + 1] = oo;
      } else {
        ws[WS_K + row_e - 4096] = oe;
        ws[WS_K + row_e - 4095] = oo;
      }
    } else {                          // v row: passthrough
      ws[WS_V + row_e - 5120] = xe;
      ws[WS_V + row_e - 5119] = xo;
    }
  }
}

// ---------------------------------------------------------------------------
// K2: flash-decode partials over the selected cache.
// grid = (32 chunks of 128 positions, 8 kv heads); block = 256 (4 waves).
// Wave w handles q head kvh*4+w. K chunk staged in 64KB LDS (xor-swizzled),
// then the SAME buffer is reloaded with V after the score phase.
// ---------------------------------------------------------------------------
__global__ __launch_bounds__(256) void attn_partial_kernel(
    const float* __restrict__ kc,
    const float* __restrict__ vc,
    const int*   __restrict__ bidx,
    float* __restrict__ ws)
{
  const int chunk = blockIdx.x;   // 0..31
  const int kvh   = blockIdx.y;   // 0..7
  const int tid   = threadIdx.x;
  const int wave  = tid >> 6;
  const int lane  = tid & 63;

  __shared__ float4 kv4[128 * 32];  // 64 KB, reused for K then V

  const int cb      = bidx[chunk >> 1];
  const int posbase = (chunk & 1) * 128;
  // element (pos, d) of head kvh in cache block cb:
  //   ((cb*256 + pos)*8 + kvh)*128 + d ;  pos stride = 1024 floats = 256 float4
  const size_t basef4 = ((((size_t)cb * KVBLK + posbase) * NKV + kvh) * HD) / 4;
  const float4* ksrc = (const float4*)kc + basef4;
  const float4* vsrc = (const float4*)vc + basef4;

  // ---- stage K (swizzled) ----
#pragma unroll
  for (int i = 0; i < 16; ++i) {
    const int idx = tid + i * 256;
    const int p   = idx >> 5;
    const int d4  = idx & 31;
    kv4[p * 32 + (d4 ^ (p & 31))] = ksrc[(size_t)p * 256 + d4];
  }
  __syncthreads();

  // ---- scores: each lane owns positions p0=lane, p1=lane+64 ----
  const int qh = kvh * 4 + wave;
  const float4* qg4 = (const float4*)(ws + WS_Q + (size_t)qh * HD);

  float s0 = 0.f, s1 = 0.f;
  const int p0 = lane, p1 = lane + 64;
#pragma unroll
  for (int d4 = 0; d4 < 32; ++d4) {
    const float4 qv = qg4[d4];  // wave-uniform address -> broadcast, L1-hot
    const float4 k0 = kv4[p0 * 32 + (d4 ^ (p0 & 31))];
    const float4 k1 = kv4[p1 * 32 + (d4 ^ (p1 & 31))];
    s0 += qv.x * k0.x + qv.y * k0.y + qv.z * k0.z + qv.w * k0.w;
    s1 += qv.x * k1.x + qv.y * k1.y + qv.z * k1.z + qv.w * k1.w;
  }
  s0 *= SCALE; s1 *= SCALE;

  // wave-level softmax over this chunk's 128 scores
  float m = fmaxf(s0, s1);
#pragma unroll
  for (int off = 32; off > 0; off >>= 1)
    m = fmaxf(m, __shfl_xor(m, off, 64));
  const float e0 = __expf(s0 - m);
  const float e1 = __expf(s1 - m);
  float l = e0 + e1;
#pragma unroll
  for (int off = 32; off > 0; off >>= 1)
    l += __shfl_xor(l, off, 64);

  // ---- stage V into the same buffer ----
  __syncthreads();  // all waves done reading K
#pragma unroll
  for (int i = 0; i < 16; ++i) {
    const int idx = tid + i * 256;
    const int p   = idx >> 5;
    const int d4  = idx & 31;
    kv4[p * 32 + d4] = vsrc[(size_t)p * 256 + d4];
  }
  __syncthreads();

  // ---- PV: lane owns dims 2*lane, 2*lane+1; e broadcast via shfl ----
  float2 o = make_float2(0.f, 0.f);
  const float2* v2 = (const float2*)kv4;
#pragma unroll 8
  for (int t = 0; t < 128; ++t) {
    const float e = (t < 64) ? __shfl(e0, t, 64) : __shfl(e1, t - 64, 64);
    const float2 vv = v2[(size_t)t * 64 + lane];
    o.x += e * vv.x;
    o.y += e * vv.y;
  }

  const int pc = qh * 32 + chunk;
  if (lane == 0) {
    ws[WS_M + pc] = m;
    ws[WS_L + pc] = l;
  }
  ((float2*)(ws + WS_O + (size_t)pc * HD))[lane] = o;
}

// ---------------------------------------------------------------------------
// K3: combine 32 chunk-partials per q head + the fresh token, normalize.
// grid = 32 heads, block = 128 threads (one per dim).
// ---------------------------------------------------------------------------
__global__ __launch_bounds__(128) void attn_reduce_kernel(float* __restrict__ ws)
{
  const int qh  = blockIdx.x;
  const int d   = threadIdx.x;
  const int kvh = qh >> 2;

  // fresh-token score: dot(q_h, k_new) via block tree-reduce
  __shared__ float red[128];
  red[d] = ws[WS_Q + qh * HD + d] * ws[WS_K + kvh * HD + d];
  __syncthreads();
  for (int off = 64; off > 0; off >>= 1) {
    if (d < off) red[d] += red[d + off];
    __syncthreads();
  }
  const float s_new = red[0] * SCALE;

  float m_g = s_new;
  for (int c = 0; c < 32; ++c)
    m_g = fmaxf(m_g, ws[WS_M + qh * 32 + c]);

  const float w_new = __expf(s_new - m_g);
  float l_g = w_new;
  float o_d = w_new * ws[WS_V + kvh * HD + d];
  for (int c = 0; c < 32; ++c) {
    const float mc = ws[WS_M + qh * 32 + c];
    const float lc = ws[WS_L + qh * 32 + c];
    const float w  = __expf(mc - m_g);
    l_g += lc * w;
    o_d += w * ws[WS_O + (size_t)(qh * 32 + c) * HD + d];
  }
  ws[WS_AO + qh * HD + d] = o_d / l_g;
}

// ---------------------------------------------------------------------------
// K4: output projection GEMV: out[i] = dot(attn_out, wo[i,:]).
// ---------------------------------------------------------------------------
__global__ __launch_bounds__(256) void oproj_kernel(
    const float* __restrict__ wo,
    const float* __restrict__ ws,
    float* __restrict__ out)
{
  const int tid  = threadIdx.x;
  const int wave = tid >> 6;
  const int lane = tid & 63;
  const int row  = blockIdx.x * 4 + wave;

  const float4* w4 = (const float4*)(wo + (size_t)row * DIM);
  const float4* a4 = (const float4*)(ws + WS_AO);

  float acc = 0.f;
#pragma unroll
  for (int i = 0; i < 16; ++i) {
    float4 a = a4[lane + i * 64];
    float4 b = w4[lane + i * 64];
    acc += a.x * b.x + a.y * b.y + a.z * b.z + a.w * b.w;
  }
#pragma unroll
  for (int off = 32; off > 0; off >>= 1)
    acc += __shfl_xor(acc, off, 64);

  if (lane == 0) out[row] = acc;
}

// ---------------------------------------------------------------------------
extern "C" void kernel_launch(void* const* d_in, const int* in_sizes, int n_in,
                              void* d_out, int out_size, void* d_ws, size_t ws_size,
                              hipStream_t stream)
{
  const float* x    = (const float*)d_in[0];
  const float* fcos = (const float*)d_in[1];
  const float* fsin = (const float*)d_in[2];
  const float* wq   = (const float*)d_in[3];
  const float* wk   = (const float*)d_in[4];
  const float* wv   = (const float*)d_in[5];
  const float* wo   = (const float*)d_in[6];
  const float* kc   = (const float*)d_in[7];
  const float* vc   = (const float*)d_in[8];
  const int*   bidx = (const int*)d_in[9];
  float* out = (float*)d_out;
  float* ws  = (float*)d_ws;

  qkv_rope_kernel<<<1536, 256, 0, stream>>>(x, wq, wk, wv, fcos, fsin, ws);
  attn_partial_kernel<<<dim3(32, 8), 256, 0, stream>>>(kc, vc, bidx, ws);
  attn_reduce_kernel<<<32, 128, 0, stream>>>(ws);
  oproj_kernel<<<1024, 256, 0, stream>>>(wo, ws, out);
}